// Round 1
// baseline (639.415 us; speedup 1.0000x reference)
//
#include <hip/hip_runtime.h>
#include <math.h>

#define NUM_E   1024
#define EDIM    64
#define N_PTS   131072          // 32*64*64
#define ZQ_ELEM 8388608         // 32*64*64*64

// ---------------------------------------------------------------- ee = ||e||^2
__global__ __launch_bounds__(256) void vq_ee(const float* __restrict__ cb,
                                             float* __restrict__ ee) {
    int j = blockIdx.x * 256 + threadIdx.x;   // grid=4 -> exactly 1024
    const float* r = cb + j * EDIM;
    float a = 0.f;
#pragma unroll
    for (int k = 0; k < EDIM; ++k) a = fmaf(r[k], r[k], a);
    ee[j] = a;
}

// ---------------------------------------------------------------- argmin
// One WG = 64 points (one (b,h) row, w=0..63), 256 threads.
// Register tile: 4 points x 8 codes per thread; codes chunked 128 at a time.
__global__ __launch_bounds__(256) void vq_argmin(
    const float* __restrict__ z, const float* __restrict__ cb,
    const float* __restrict__ ee, float* __restrict__ idx_f,
    int* __restrict__ counts)
{
    __shared__ float zt[64 * 64];     // [k][p] 16 KB
    __shared__ float zzs[64];
    __shared__ float et[64 * 128];    // [k][j] 32 KB (reused for reduction)
    __shared__ float eet[128];

    const int tid = threadIdx.x;
    const int g   = blockIdx.x;                       // 2048 blocks
    const float* zb = z + ((size_t)(g >> 6) << 18) + (size_t)((g & 63) << 6);

    // stage z tile: zt[c][w], coalesced over w
    {
        const int w = tid & 63, cq = tid >> 6;
#pragma unroll
        for (int i = 0; i < 16; ++i) {
            int c = cq * 16 + i;
            zt[c * 64 + w] = zb[((size_t)c << 12) + w];
        }
    }
    __syncthreads();
    if (tid < 64) {                                   // zz per point
        float a = 0.f;
#pragma unroll
        for (int k = 0; k < 64; ++k) { float v = zt[k * 64 + tid]; a = fmaf(v, v, a); }
        zzs[tid] = a;
    }
    __syncthreads();

    const int tx = tid & 15, ty = tid >> 4;
    float zzp[4];
#pragma unroll
    for (int p = 0; p < 4; ++p) zzp[p] = zzs[ty * 4 + p];

    float best[4]; int bidx[4];
#pragma unroll
    for (int p = 0; p < 4; ++p) { best[p] = 3.4e38f; bidx[p] = 0; }

    for (int ch = 0; ch < 8; ++ch) {
        __syncthreads();                               // protect et reuse
        {   // stage transposed code chunk: et[k][j]
            const int j = tid >> 1, kh = (tid & 1) * 32;
            const float* cr = cb + ((size_t)(ch * 128 + j) << 6) + kh;
#pragma unroll
            for (int i = 0; i < 8; ++i) {
                float4 v = *(const float4*)(cr + i * 4);
                et[(kh + i * 4 + 0) * 128 + j] = v.x;
                et[(kh + i * 4 + 1) * 128 + j] = v.y;
                et[(kh + i * 4 + 2) * 128 + j] = v.z;
                et[(kh + i * 4 + 3) * 128 + j] = v.w;
            }
            if (tid < 128) eet[tid] = ee[ch * 128 + tid];
        }
        __syncthreads();

        float eev[8];
#pragma unroll
        for (int i = 0; i < 4; ++i) { eev[i] = eet[tx * 4 + i]; eev[4 + i] = eet[64 + tx * 4 + i]; }

        float acc[4][8];
#pragma unroll
        for (int p = 0; p < 4; ++p)
#pragma unroll
            for (int c = 0; c < 8; ++c) acc[p][c] = 0.f;

#pragma unroll 4
        for (int k = 0; k < 64; ++k) {
            float4 za = *(const float4*)&zt[k * 64 + ty * 4];
            float4 e0 = *(const float4*)&et[k * 128 + tx * 4];
            float4 e1 = *(const float4*)&et[k * 128 + 64 + tx * 4];
            float zav[4] = { za.x, za.y, za.z, za.w };
            float ev[8]  = { e0.x, e0.y, e0.z, e0.w, e1.x, e1.y, e1.z, e1.w };
#pragma unroll
            for (int p = 0; p < 4; ++p)
#pragma unroll
                for (int c = 0; c < 8; ++c)
                    acc[p][c] = fmaf(zav[p], ev[c], acc[p][c]);
        }

        // d = (zz+ee) - 2*dot, exact fp32 mimicry; ascending j scan, strict <
#pragma unroll
        for (int p = 0; p < 4; ++p) {
#pragma unroll
            for (int c = 0; c < 8; ++c) {
                int j = ch * 128 + ((c < 4) ? (tx * 4 + c) : (64 + tx * 4 + (c - 4)));
                float t1 = zzp[p] + eev[c];
                float d  = fmaf(-2.f, acc[p][c], t1);   // == fl(t1 - 2*dot), 2*dot exact
                if (d < best[p]) { best[p] = d; bidx[p] = j; }
            }
        }
    }

    __syncthreads();
    float* rv = et;                        // [64][17]
    int*   ri = (int*)(et + 64 * 17);      // [64][17]
#pragma unroll
    for (int p = 0; p < 4; ++p) {
        rv[(ty * 4 + p) * 17 + tx] = best[p];
        ri[(ty * 4 + p) * 17 + tx] = bidx[p];
    }
    __syncthreads();
    if (tid < 64) {
        float bv = rv[tid * 17]; int bi = ri[tid * 17];
#pragma unroll
        for (int t = 1; t < 16; ++t) {
            float v = rv[tid * 17 + t]; int i2 = ri[tid * 17 + t];
            if (v < bv || (v == bv && i2 < bi)) { bv = v; bi = i2; }  // lowest-idx tie-break
        }
        int n = g * 64 + tid;              // n = b*4096 + h*64 + w
        idx_f[n] = (float)bi;
        atomicAdd(&counts[bi], 1);
    }
}

// ---------------------------------------------------------------- gather + ST + loss
__global__ __launch_bounds__(256) void vq_quant(
    const float* __restrict__ z, const float* __restrict__ cb,
    const float* __restrict__ idx_f, float* __restrict__ zq,
    double* __restrict__ lacc)
{
    int m4 = blockIdx.x * 256 + threadIdx.x;   // 2,097,152 float4s, grid=8192
    int w4 = m4 & 15;
    int h  = (m4 >> 4) & 63;
    int c  = (m4 >> 10) & 63;
    int b  = m4 >> 16;
    float4 z4 = ((const float4*)z)[m4];
    int n = (b << 12) + (h << 6) + (w4 << 2);
    float4 if4 = *(const float4*)(idx_f + n);
    int i0 = (int)if4.x, i1 = (int)if4.y, i2 = (int)if4.z, i3 = (int)if4.w;
    float q0 = cb[(i0 << 6) + c];
    float q1 = cb[(i1 << 6) + c];
    float q2 = cb[(i2 << 6) + c];
    float q3 = cb[(i3 << 6) + c];
    float t0 = q0 - z4.x, t1 = q1 - z4.y, t2 = q2 - z4.z, t3 = q3 - z4.w;
    float4 o = make_float4(z4.x + t0, z4.y + t1, z4.z + t2, z4.w + t3); // fl(z + fl(zq-z))
    ((float4*)zq)[m4] = o;
    double pd = (double)t0 * t0 + (double)t1 * t1 + (double)t2 * t2 + (double)t3 * t3;
#pragma unroll
    for (int off = 32; off > 0; off >>= 1) pd += __shfl_down(pd, off);
    if ((threadIdx.x & 63) == 0) atomicAdd(lacc, pd);
}

// ---------------------------------------------------------------- scalars
__global__ __launch_bounds__(256) void vq_final(
    const int* __restrict__ counts, const double* __restrict__ lacc,
    float* __restrict__ scalars)
{
    __shared__ double sh[256];
    int t = threadIdx.x;
    double s = 0.0;
    for (int j = t; j < NUM_E; j += 256) {
        float em   = (float)counts[j] * (1.0f / 131072.0f);  // exact pow2 division
        float term = em * logf(em + 1e-10f);
        s += (double)term;
    }
    sh[t] = s;
    __syncthreads();
    for (int off = 128; off > 0; off >>= 1) {
        if (t < off) sh[t] += sh[t + off];
        __syncthreads();
    }
    if (t == 0) {
        float m = (float)(lacc[0] / 8388608.0);
        scalars[0] = m + 0.5f * m;           // mean1 + BETA*mean2
        scalars[1] = expf(-(float)sh[0]);    // perplexity
    }
}

// ---------------------------------------------------------------- launch
extern "C" void kernel_launch(void* const* d_in, const int* in_sizes, int n_in,
                              void* d_out, int out_size, void* d_ws, size_t ws_size,
                              hipStream_t stream)
{
    const float* z  = (const float*)d_in[0];
    const float* cb = (const float*)d_in[1];
    float* out     = (float*)d_out;
    float* zq      = out;                    // [32,64,64,64]
    float* scalars = out + ZQ_ELEM;          // loss, perplexity
    float* idx_f   = out + ZQ_ELEM + 2;      // [32,64,64] as float

    int*    counts = (int*)d_ws;                      // 4096 B
    double* lacc   = (double*)((char*)d_ws + 4096);   // 8 B
    float*  ee     = (float*)((char*)d_ws + 4160);    // 4096 B

    hipMemsetAsync(d_ws, 0, 4104, stream);            // zero counts + lacc
    vq_ee    <<<4,    256, 0, stream>>>(cb, ee);
    vq_argmin<<<2048, 256, 0, stream>>>(z, cb, ee, idx_f, counts);
    vq_quant <<<8192, 256, 0, stream>>>(z, cb, idx_f, zq, lacc);
    vq_final <<<1,    256, 0, stream>>>(counts, lacc, scalars);
}

// Round 2
// 270.823 us; speedup vs baseline: 2.3610x; 2.3610x over previous
//
#include <hip/hip_runtime.h>
#include <math.h>

#define NUM_E   1024
#define EDIM    64
#define N_PTS   131072          // 32*64*64
#define ZQ_ELEM 8388608         // 32*64*64*64
#define QGRID   8192

// ---------------------------------------------------------------- ee = ||e||^2
__global__ __launch_bounds__(256) void vq_ee(const float* __restrict__ cb,
                                             float* __restrict__ ee) {
    int j = blockIdx.x * 256 + threadIdx.x;   // grid=4 -> exactly 1024
    const float* r = cb + j * EDIM;
    float a = 0.f;
#pragma unroll
    for (int k = 0; k < EDIM; ++k) a = fmaf(r[k], r[k], a);
    ee[j] = a;
}

// ---------------------------------------------------------------- argmin
// One WG = 64 points (one (b,h) row, w=0..63), 256 threads.
// Register tile: 4 points x 8 codes per thread; codes chunked 128 at a time.
__global__ __launch_bounds__(256) void vq_argmin(
    const float* __restrict__ z, const float* __restrict__ cb,
    const float* __restrict__ ee, float* __restrict__ idx_f,
    int* __restrict__ counts)
{
    __shared__ float zt[64 * 64];     // [k][p] 16 KB
    __shared__ float zzs[64];
    __shared__ float et[64 * 128];    // [k][j] 32 KB (reused for reduction)
    __shared__ float eet[128];

    const int tid = threadIdx.x;
    const int g   = blockIdx.x;                       // 2048 blocks
    const float* zb = z + ((size_t)(g >> 6) << 18) + (size_t)((g & 63) << 6);

    // stage z tile: zt[c][w], coalesced over w
    {
        const int w = tid & 63, cq = tid >> 6;
#pragma unroll
        for (int i = 0; i < 16; ++i) {
            int c = cq * 16 + i;
            zt[c * 64 + w] = zb[((size_t)c << 12) + w];
        }
    }
    __syncthreads();
    if (tid < 64) {                                   // zz per point
        float a = 0.f;
#pragma unroll
        for (int k = 0; k < 64; ++k) { float v = zt[k * 64 + tid]; a = fmaf(v, v, a); }
        zzs[tid] = a;
    }
    __syncthreads();

    const int tx = tid & 15, ty = tid >> 4;
    float zzp[4];
#pragma unroll
    for (int p = 0; p < 4; ++p) zzp[p] = zzs[ty * 4 + p];

    float best[4]; int bidx[4];
#pragma unroll
    for (int p = 0; p < 4; ++p) { best[p] = 3.4e38f; bidx[p] = 0; }

    for (int ch = 0; ch < 8; ++ch) {
        __syncthreads();                               // protect et reuse
        {   // stage transposed code chunk: et[k][j]
            const int j = tid >> 1, kh = (tid & 1) * 32;
            const float* cr = cb + ((size_t)(ch * 128 + j) << 6) + kh;
#pragma unroll
            for (int i = 0; i < 8; ++i) {
                float4 v = *(const float4*)(cr + i * 4);
                et[(kh + i * 4 + 0) * 128 + j] = v.x;
                et[(kh + i * 4 + 1) * 128 + j] = v.y;
                et[(kh + i * 4 + 2) * 128 + j] = v.z;
                et[(kh + i * 4 + 3) * 128 + j] = v.w;
            }
            if (tid < 128) eet[tid] = ee[ch * 128 + tid];
        }
        __syncthreads();

        float eev[8];
#pragma unroll
        for (int i = 0; i < 4; ++i) { eev[i] = eet[tx * 4 + i]; eev[4 + i] = eet[64 + tx * 4 + i]; }

        float acc[4][8];
#pragma unroll
        for (int p = 0; p < 4; ++p)
#pragma unroll
            for (int c = 0; c < 8; ++c) acc[p][c] = 0.f;

#pragma unroll 4
        for (int k = 0; k < 64; ++k) {
            float4 za = *(const float4*)&zt[k * 64 + ty * 4];
            float4 e0 = *(const float4*)&et[k * 128 + tx * 4];
            float4 e1 = *(const float4*)&et[k * 128 + 64 + tx * 4];
            float zav[4] = { za.x, za.y, za.z, za.w };
            float ev[8]  = { e0.x, e0.y, e0.z, e0.w, e1.x, e1.y, e1.z, e1.w };
#pragma unroll
            for (int p = 0; p < 4; ++p)
#pragma unroll
                for (int c = 0; c < 8; ++c)
                    acc[p][c] = fmaf(zav[p], ev[c], acc[p][c]);
        }

        // d = (zz+ee) - 2*dot, exact fp32 mimicry; ascending j scan, strict <
#pragma unroll
        for (int p = 0; p < 4; ++p) {
#pragma unroll
            for (int c = 0; c < 8; ++c) {
                int j = ch * 128 + ((c < 4) ? (tx * 4 + c) : (64 + tx * 4 + (c - 4)));
                float t1 = zzp[p] + eev[c];
                float d  = fmaf(-2.f, acc[p][c], t1);   // == fl(t1 - 2*dot), 2*dot exact
                if (d < best[p]) { best[p] = d; bidx[p] = j; }
            }
        }
    }

    __syncthreads();
    float* rv = et;                        // [64][17]
    int*   ri = (int*)(et + 64 * 17);      // [64][17]
#pragma unroll
    for (int p = 0; p < 4; ++p) {
        rv[(ty * 4 + p) * 17 + tx] = best[p];
        ri[(ty * 4 + p) * 17 + tx] = bidx[p];
    }
    __syncthreads();
    if (tid < 64) {
        float bv = rv[tid * 17]; int bi = ri[tid * 17];
#pragma unroll
        for (int t = 1; t < 16; ++t) {
            float v = rv[tid * 17 + t]; int i2 = ri[tid * 17 + t];
            if (v < bv || (v == bv && i2 < bi)) { bv = v; bi = i2; }  // lowest-idx tie-break
        }
        int n = g * 64 + tid;              // n = b*4096 + h*64 + w
        idx_f[n] = (float)bi;
        atomicAdd(&counts[bi], 1);
    }
}

// ---------------------------------------------------------------- gather + ST + loss
// No global atomics: block-level reduction -> partials[blockIdx.x]
__global__ __launch_bounds__(256) void vq_quant(
    const float* __restrict__ z, const float* __restrict__ cb,
    const float* __restrict__ idx_f, float* __restrict__ zq,
    double* __restrict__ partials)
{
    __shared__ double wsum[4];
    int m4 = blockIdx.x * 256 + threadIdx.x;   // 2,097,152 float4s, grid=8192
    int w4 = m4 & 15;
    int h  = (m4 >> 4) & 63;
    int c  = (m4 >> 10) & 63;
    int b  = m4 >> 16;
    float4 z4 = ((const float4*)z)[m4];
    int n = (b << 12) + (h << 6) + (w4 << 2);
    float4 if4 = *(const float4*)(idx_f + n);
    int i0 = (int)if4.x, i1 = (int)if4.y, i2 = (int)if4.z, i3 = (int)if4.w;
    float q0 = cb[(i0 << 6) + c];
    float q1 = cb[(i1 << 6) + c];
    float q2 = cb[(i2 << 6) + c];
    float q3 = cb[(i3 << 6) + c];
    float t0 = q0 - z4.x, t1 = q1 - z4.y, t2 = q2 - z4.z, t3 = q3 - z4.w;
    float4 o = make_float4(z4.x + t0, z4.y + t1, z4.z + t2, z4.w + t3); // fl(z + fl(zq-z))
    ((float4*)zq)[m4] = o;
    double pd = (double)t0 * t0 + (double)t1 * t1 + (double)t2 * t2 + (double)t3 * t3;
#pragma unroll
    for (int off = 32; off > 0; off >>= 1) pd += __shfl_down(pd, off);
    if ((threadIdx.x & 63) == 0) wsum[threadIdx.x >> 6] = pd;
    __syncthreads();
    if (threadIdx.x == 0)
        partials[blockIdx.x] = wsum[0] + wsum[1] + wsum[2] + wsum[3];
}

// ---------------------------------------------------------------- scalars
__global__ __launch_bounds__(256) void vq_final(
    const int* __restrict__ counts, const double* __restrict__ partials,
    float* __restrict__ scalars)
{
    __shared__ double sh[256];
    __shared__ double sl[256];
    int t = threadIdx.x;
    double s = 0.0;
    for (int j = t; j < NUM_E; j += 256) {
        float em   = (float)counts[j] * (1.0f / 131072.0f);  // exact pow2 division
        float term = em * logf(em + 1e-10f);
        s += (double)term;
    }
    double l = 0.0;
#pragma unroll
    for (int j = 0; j < QGRID / 256; ++j) l += partials[j * 256 + t];
    sh[t] = s;
    sl[t] = l;
    __syncthreads();
    for (int off = 128; off > 0; off >>= 1) {
        if (t < off) { sh[t] += sh[t + off]; sl[t] += sl[t + off]; }
        __syncthreads();
    }
    if (t == 0) {
        float m = (float)(sl[0] / 8388608.0);
        scalars[0] = m + 0.5f * m;           // mean1 + BETA*mean2
        scalars[1] = expf(-(float)sh[0]);    // perplexity
    }
}

// ---------------------------------------------------------------- launch
extern "C" void kernel_launch(void* const* d_in, const int* in_sizes, int n_in,
                              void* d_out, int out_size, void* d_ws, size_t ws_size,
                              hipStream_t stream)
{
    const float* z  = (const float*)d_in[0];
    const float* cb = (const float*)d_in[1];
    float* out     = (float*)d_out;
    float* zq      = out;                    // [32,64,64,64]
    float* scalars = out + ZQ_ELEM;          // loss, perplexity
    float* idx_f   = out + ZQ_ELEM + 2;      // [32,64,64] as float

    int*    counts   = (int*)d_ws;                          // 4096 B
    double* partials = (double*)((char*)d_ws + 4096);       // 8192*8 = 64 KB
    float*  ee       = (float*)((char*)d_ws + 4096 + QGRID * 8);

    hipMemsetAsync(d_ws, 0, 4096, stream);            // zero counts
    vq_ee    <<<4,     256, 0, stream>>>(cb, ee);
    vq_argmin<<<2048,  256, 0, stream>>>(z, cb, ee, idx_f, counts);
    vq_quant <<<QGRID, 256, 0, stream>>>(z, cb, idx_f, zq, partials);
    vq_final <<<1,     256, 0, stream>>>(counts, partials, scalars);
}